// Round 2
// baseline (425.074 us; speedup 1.0000x reference)
//
#include <hip/hip_runtime.h>
#include <cstddef>

// B=256, N=32, F=40, H=100, M=100, EF=4, OUT=128, 3 passes.
#define B_   256
#define N_   32
#define F_   40
#define H_   100
#define M_   100
#define EF_  4
#define OUT_ 128
#define CAP_ 8
#define TB   512
#define ST   36   // LDS row stride (floats): rows 16B-aligned; bank=(4h+n)%32

__device__ __forceinline__ float sigmoidf_(float x) { return 1.0f / (1.0f + __expf(-x)); }

// ---------------------------------------------------------------------------
// Repack weights k-major per output column so each GEMM thread streams
// contiguous float4s along k (4x fewer load events, L1 line reuse).
//   WmP [jm][t][k]    (100*4*100)   msg:   = W_msg[jm, k, t]
//   WgP [jm][g][k]    (100*6*100)   GRU:   g<3 -> W_ih[g*100+jm, k], else W_hh
//   WgoP[jm][k]       (100*140)     gate:  = Wg[k, jm]
//   WeP [jm][k]       (100*100)     emb:   = We[k, jm]
// ---------------------------------------------------------------------------
__global__ void prep_weights(const float* __restrict__ Wmsg,
                             const float* __restrict__ Wih,
                             const float* __restrict__ Whh,
                             const float* __restrict__ Wg,
                             const float* __restrict__ We,
                             float* __restrict__ WmP,
                             float* __restrict__ WgP,
                             float* __restrict__ WgoP,
                             float* __restrict__ WeP) {
  int i = blockIdx.x * blockDim.x + threadIdx.x;
  if (i < M_ * EF_ * H_) {                 // dst (m*4+t)*100+h ; src (m*H+h)*EF+t
    int m = i / 400, r = i % 400, t = r / 100, h = r % 100;
    WmP[i] = Wmsg[(m * H_ + h) * EF_ + t];
  }
  if (i < 100 * 600) {                     // dst (jm*6+g)*100+k
    int jm = i / 600, r = i % 600, g = r / 100, k = r % 100;
    WgP[i] = (g < 3) ? Wih[(g * 100 + jm) * 100 + k]
                     : Whh[((g - 3) * 100 + jm) * 100 + k];
  }
  if (i < 100 * 140) {                     // dst jm*140+k ; src k*100+jm
    int jm = i / 140, k = i % 140;
    WgoP[i] = Wg[k * 100 + jm];
  }
  if (i < 100 * 100) {
    int jm = i / 100, k = i % 100;
    WeP[i] = We[k * 100 + jm];
  }
}

// ---------------------------------------------------------------------------
// Fused MPNN, one block per batch. Activations in LDS [feat][node] stride-36.
// Hidden/scratch buffers swap roles each pass (scratch = Y aggregate, then
// new-hidden) -> no copy, no double-buffer waste.
// ---------------------------------------------------------------------------
__global__ __launch_bounds__(TB) void mpnn_fused(
    const float* __restrict__ nodes, const float* __restrict__ edges,
    const float* __restrict__ WmP, const float* __restrict__ WgP,
    const float* __restrict__ b_ih, const float* __restrict__ b_hh,
    const float* __restrict__ WgoP, const float* __restrict__ bg,
    const float* __restrict__ WeP, const float* __restrict__ be,
    const float* __restrict__ Wo, const float* __restrict__ bo,
    float* __restrict__ out) {
  const int b = blockIdx.x;
  const int tid = threadIdx.x;

  __shared__ float buf[2][H_][ST];    // hidden + scratch(Y/new-h)  28.8 KB
  __shared__ float msgT[M_][ST];      // messages [m][n]            14.4 KB
  __shared__ float nodesT[F_][ST];    // node feats [f][n]           5.8 KB
  __shared__ float sh_ge[H_];
  __shared__ float sh_rowsum[N_];
  __shared__ int sh_cnt[N_];
  __shared__ int sh_gt[N_][CAP_];     // packed (g<<2)|t
  __shared__ float sh_w[N_][CAP_];

  if (tid < N_) { sh_cnt[tid] = 0; sh_rowsum[tid] = 0.0f; }
  __syncthreads();

  // ---- per-node neighbor lists ---------------------------------------------
  for (int p = tid; p < N_ * N_; p += TB) {
    int n = p >> 5, g = p & 31;
    const float* e = edges + (((size_t)b * N_ + n) * N_ + g) * EF_;
    float e0 = e[0], e1 = e[1], e2 = e[2], e3 = e[3];
    float adj = e0 + e1 + e2 + e3;
    if (adj != 0.0f) {
      atomicAdd(&sh_rowsum[n], adj);
      float ef[4] = {e0, e1, e2, e3};
      for (int f = 0; f < 4; ++f)
        if (ef[f] != 0.0f) {
          int s = atomicAdd(&sh_cnt[n], 1);
          if (s < CAP_) { sh_gt[n][s] = (g << 2) | f; sh_w[n][s] = ef[f]; }
        }
    }
  }
  for (int p = tid; p < N_ * F_; p += TB) {
    int n = p / F_, f = p % F_;
    nodesT[f][n] = nodes[((size_t)b * N_ + n) * F_ + f];
  }
  __syncthreads();
  for (int p = tid; p < N_ * H_; p += TB) {   // hidden init: h[:F]=nodes
    int h = p >> 5, n = p & 31;
    buf[0][h][n] = (h < F_) ? nodesT[h][n] : 0.0f;
  }

  const int jm = tid % 100;
  const int n0 = (tid < 400) ? (tid / 100) * 8 : 0;
  const bool active = tid < 400;
  int cur = 0;

  for (int pass = 0; pass < 3; ++pass) {
    const int scr = cur ^ 1;
    float acc[8] = {0.f, 0.f, 0.f, 0.f, 0.f, 0.f, 0.f, 0.f};
    // ---- messages: per type, aggregate Y into scratch then GEMM-accumulate -
    for (int t = 0; t < 4; ++t) {
      __syncthreads();
      for (int p = tid; p < N_ * H_; p += TB) {
        int h = p >> 5, n = p & 31;
        int cnt = sh_cnt[n] < CAP_ ? sh_cnt[n] : CAP_;
        float s = 0.0f;
        for (int e = 0; e < cnt; ++e) {
          int gt = sh_gt[n][e];
          if ((gt & 3) == t) s += sh_w[n][e] * buf[cur][h][gt >> 2];
        }
        buf[scr][h][n] = s;
      }
      __syncthreads();
      if (active) {
        const float4* wp = (const float4*)(WmP + (jm * 4 + t) * 100);
        float4 w = wp[0];
        for (int q = 0; q < 25; ++q) {
          float4 wn = (q < 24) ? wp[q + 1] : w;
#pragma unroll
          for (int kk = 0; kk < 4; ++kk) {
            int k = 4 * q + kk;
            float wv = ((const float*)&w)[kk];
            float yv[8];
            *(float4*)&yv[0] = *(const float4*)&buf[scr][k][n0];
            *(float4*)&yv[4] = *(const float4*)&buf[scr][k][n0 + 4];
#pragma unroll
            for (int i = 0; i < 8; ++i) acc[i] += wv * yv[i];
          }
          w = wn;
        }
      }
    }
    __syncthreads();
    if (active) {
#pragma unroll
      for (int i = 0; i < 8; ++i) msgT[jm][n0 + i] = acc[i];
    }
    __syncthreads();
    // ---- GRU ---------------------------------------------------------------
    if (active) {
      float air[8] = {0,0,0,0,0,0,0,0}, aiz[8] = {0,0,0,0,0,0,0,0},
            ain[8] = {0,0,0,0,0,0,0,0}, ahr[8] = {0,0,0,0,0,0,0,0},
            ahz[8] = {0,0,0,0,0,0,0,0}, ahn[8] = {0,0,0,0,0,0,0,0};
      const float4* wp = (const float4*)(WgP + jm * 600);
      float4 w0 = wp[0], w1 = wp[25], w2 = wp[50],
             w3 = wp[75], w4 = wp[100], w5 = wp[125];
      for (int q = 0; q < 25; ++q) {
        float4 p0, p1, p2, p3, p4, p5;
        if (q < 24) {
          p0 = wp[q + 1];   p1 = wp[q + 26];  p2 = wp[q + 51];
          p3 = wp[q + 76];  p4 = wp[q + 101]; p5 = wp[q + 126];
        }
#pragma unroll
        for (int kk = 0; kk < 4; ++kk) {
          int k = 4 * q + kk;
          float wir = ((const float*)&w0)[kk], wiz = ((const float*)&w1)[kk],
                win = ((const float*)&w2)[kk], whr = ((const float*)&w3)[kk],
                whz = ((const float*)&w4)[kk], whn = ((const float*)&w5)[kk];
          float xv[8], hv[8];
          *(float4*)&xv[0] = *(const float4*)&msgT[k][n0];
          *(float4*)&xv[4] = *(const float4*)&msgT[k][n0 + 4];
          *(float4*)&hv[0] = *(const float4*)&buf[cur][k][n0];
          *(float4*)&hv[4] = *(const float4*)&buf[cur][k][n0 + 4];
#pragma unroll
          for (int i = 0; i < 8; ++i) {
            air[i] += wir * xv[i];
            aiz[i] += wiz * xv[i];
            ain[i] += win * xv[i];
            ahr[i] += whr * hv[i];
            ahz[i] += whz * hv[i];
            ahn[i] += whn * hv[i];
          }
        }
        if (q < 24) { w0 = p0; w1 = p1; w2 = p2; w3 = p3; w4 = p4; w5 = p5; }
      }
      float bir = b_ih[jm], biz = b_ih[100 + jm], bin_ = b_ih[200 + jm];
      float bhr = b_hh[jm], bhz = b_hh[100 + jm], bhn = b_hh[200 + jm];
#pragma unroll
      for (int i = 0; i < 8; ++i) {
        int n = n0 + i;
        float ho = buf[cur][jm][n];
        float r = sigmoidf_(air[i] + bir + ahr[i] + bhr);
        float z = sigmoidf_(aiz[i] + biz + ahz[i] + bhz);
        float nn2 = tanhf(ain[i] + bin_ + r * (ahn[i] + bhn));
        float hnew = (1.0f - z) * nn2 + z * ho;
        buf[scr][jm][n] = (sh_rowsum[n] != 0.0f) ? hnew : ho;
      }
    }
    __syncthreads();
    cur ^= 1;
  }

  // ---- readout -------------------------------------------------------------
  if (tid < H_) sh_ge[tid] = 0.0f;
  __syncthreads();
  if (active) {
    float ag[8] = {0,0,0,0,0,0,0,0}, ae[8] = {0,0,0,0,0,0,0,0};
    const float4* wgp = (const float4*)(WgoP + jm * 140);  // 35 float4
    const float4* wep = (const float4*)(WeP + jm * 100);   // 25 float4
    float4 wg = wgp[0], we = wep[0];
    for (int q = 0; q < 25; ++q) {
      float4 wgn = wgp[q < 24 ? q + 1 : 25];
      float4 wen = (q < 24) ? wep[q + 1] : we;
#pragma unroll
      for (int kk = 0; kk < 4; ++kk) {
        int k = 4 * q + kk;
        float a = ((const float*)&wg)[kk], c = ((const float*)&we)[kk];
        float hv[8];
        *(float4*)&hv[0] = *(const float4*)&buf[cur][k][n0];
        *(float4*)&hv[4] = *(const float4*)&buf[cur][k][n0 + 4];
#pragma unroll
        for (int i = 0; i < 8; ++i) { ag[i] += a * hv[i]; ae[i] += c * hv[i]; }
      }
      wg = wgn; we = wen;
    }
    for (int q = 25; q < 35; ++q) {          // cat tail: nodes (k=100..139)
      float4 w4 = wgp[q];
#pragma unroll
      for (int kk = 0; kk < 4; ++kk) {
        int f = 4 * q + kk - 100;
        float a = ((const float*)&w4)[kk];
        float nv[8];
        *(float4*)&nv[0] = *(const float4*)&nodesT[f][n0];
        *(float4*)&nv[4] = *(const float4*)&nodesT[f][n0 + 4];
#pragma unroll
        for (int i = 0; i < 8; ++i) ag[i] += a * nv[i];
      }
    }
    float bgj = bg[jm], bej = be[jm];
    float psum = 0.0f;
#pragma unroll
    for (int i = 0; i < 8; ++i) {
      int n = n0 + i;
      float gate = sigmoidf_(ag[i] + bgj);
      float emb = gate * (ae[i] + bej);
      if (sh_rowsum[n] != 0.0f) psum += emb;
    }
    atomicAdd(&sh_ge[jm], psum);
  }
  __syncthreads();
  if (tid < OUT_) {
    float s = bo[tid];
    for (int k = 0; k < H_; ++k) s += sh_ge[k] * Wo[k * OUT_ + tid];
    out[(size_t)b * OUT_ + tid] = s;
  }
}

extern "C" void kernel_launch(void* const* d_in, const int* in_sizes, int n_in,
                              void* d_out, int out_size, void* d_ws, size_t ws_size,
                              hipStream_t stream) {
  const float* nodes = (const float*)d_in[0];
  const float* edges = (const float*)d_in[1];
  const float* W_msg = (const float*)d_in[2];
  const float* W_ih  = (const float*)d_in[3];
  const float* W_hh  = (const float*)d_in[4];
  const float* b_ih  = (const float*)d_in[5];
  const float* b_hh  = (const float*)d_in[6];
  const float* Wg    = (const float*)d_in[7];
  const float* bg    = (const float*)d_in[8];
  const float* We    = (const float*)d_in[9];
  const float* be    = (const float*)d_in[10];
  const float* Wo    = (const float*)d_in[11];
  const float* bo    = (const float*)d_in[12];

  float* WmP  = (float*)d_ws;          // 40000 floats
  float* WgP  = WmP + 40000;           // 60000 floats
  float* WgoP = WgP + 60000;           // 14000 floats
  float* WeP  = WgoP + 14000;          // 10000 floats

  prep_weights<<<(60000 + 255) / 256, 256, 0, stream>>>(
      W_msg, W_ih, W_hh, Wg, We, WmP, WgP, WgoP, WeP);
  mpnn_fused<<<B_, TB, 0, stream>>>(nodes, edges, WmP, WgP, b_ih, b_hh,
                                    WgoP, bg, WeP, be, Wo, bo, (float*)d_out);
}

// Round 4
// 246.606 us; speedup vs baseline: 1.7237x; 1.7237x over previous
//
#include <hip/hip_runtime.h>
#include <cstddef>

// B=256, N=32, F=40, H=100, M=100, EF=4, OUT=128, 3 passes.
#define B_   256
#define N_   32
#define F_   40
#define H_   100
#define M_   100
#define EF_  4
#define OUT_ 128
#define CAP_ 8
#define TB   1024  // 16 waves/CU -> 4 waves/SIMD latency hiding
#define ST   36    // LDS row stride (floats): 16B-aligned rows, breaks 32-stride conflicts

__device__ __forceinline__ float sigmoidf_(float x) { return 1.0f / (1.0f + __expf(-x)); }

// ---------------------------------------------------------------------------
// Weight transposes to k-major-across-jm (lane-coalesced) layouts:
//   WmsgT[(t*H + h)*M + m] = W_msg[m,h,t]
//   WihT [k*300 + j]       = W_ih[j,k]
//   WhhT [k*300 + j]       = W_hh[j,k]
// (Wg, We, Wo are already k-major in the reference -> no repack.)
// ---------------------------------------------------------------------------
__global__ void prep_weights(const float* __restrict__ Wmsg,
                             const float* __restrict__ Wih,
                             const float* __restrict__ Whh,
                             float* __restrict__ WmsgT,
                             float* __restrict__ WihT,
                             float* __restrict__ WhhT) {
  int i = blockIdx.x * blockDim.x + threadIdx.x;
  if (i < M_ * H_ * EF_) {            // src (m*H + h)*EF + t
    int t = i & 3;
    int mh = i >> 2;
    int h = mh % H_;
    int m = mh / H_;
    WmsgT[(t * H_ + h) * M_ + m] = Wmsg[i];
  }
  if (i < 3 * H_ * M_) {              // src j*100 + k
    int k = i % M_;
    int j = i / M_;
    WihT[k * 300 + j] = Wih[i];
    WhhT[k * 300 + j] = Whh[i];
  }
}

// ---------------------------------------------------------------------------
// Fused MPNN, one block per batch, 1024 threads.
// Task map: jm = tid&127 (<100 active), node-group ng = tid>>7 (4 nodes).
// Every wave has uniform ng -> activation float4 reads are wave-uniform LDS
// broadcasts (free); weight reads are lane-coalesced global dwords.
// acc[4] x 6 streams keeps GRU register pressure ~64 VGPR -> no spill.
// NOTE: all block-wide staging/init MUST be grid-stride loops (bounds > TB) —
// R2's single-shot `if (tid < 1280/3200)` guards left LDS uninitialized.
// ---------------------------------------------------------------------------
__global__ __launch_bounds__(TB, 4) void mpnn_fused(
    const float* __restrict__ nodes, const float* __restrict__ edges,
    const float* __restrict__ WmsgT, const float* __restrict__ WihT,
    const float* __restrict__ WhhT, const float* __restrict__ b_ih,
    const float* __restrict__ b_hh, const float* __restrict__ Wg,
    const float* __restrict__ bg, const float* __restrict__ We,
    const float* __restrict__ be, const float* __restrict__ Wo,
    const float* __restrict__ bo, float* __restrict__ out) {
  const int b = blockIdx.x;
  const int tid = threadIdx.x;

  __shared__ float buf[2][H_][ST];    // hidden + scratch (Y / new-h)  28.8 KB
  __shared__ float msgT[M_][ST];      // messages [m][n]               14.4 KB
  __shared__ float nodesT[F_][ST];    // node feats [f][n]              5.8 KB
  __shared__ float sh_ge[H_];
  __shared__ float sh_rowsum[N_];
  __shared__ int sh_cnt[N_];
  __shared__ int sh_gt[N_][CAP_];     // packed (g<<2)|t
  __shared__ float sh_w[N_][CAP_];

  if (tid < N_) { sh_cnt[tid] = 0; sh_rowsum[tid] = 0.0f; }
  __syncthreads();

  // ---- per-node neighbor lists (one (n,g) cell per thread; 1024 == N*N) ----
  {
    int n = tid >> 5, g = tid & 31;
    const float* e = edges + (((size_t)b * N_ + n) * N_ + g) * EF_;
    float e0 = e[0], e1 = e[1], e2 = e[2], e3 = e[3];
    float adj = e0 + e1 + e2 + e3;
    if (adj != 0.0f) {
      atomicAdd(&sh_rowsum[n], adj);
      float ef[4] = {e0, e1, e2, e3};
      for (int f = 0; f < 4; ++f)
        if (ef[f] != 0.0f) {
          int s = atomicAdd(&sh_cnt[n], 1);
          if (s < CAP_) { sh_gt[n][s] = (g << 2) | f; sh_w[n][s] = ef[f]; }
        }
    }
  }
  for (int p = tid; p < N_ * F_; p += TB) {      // grid-stride: 1280 > TB
    int n = p / F_, f = p % F_;
    nodesT[f][n] = nodes[((size_t)b * N_ + n) * F_ + f];
  }
  __syncthreads();
  for (int p = tid; p < N_ * H_; p += TB) {      // grid-stride: 3200 > TB
    int h = p >> 5, n = p & 31;
    buf[0][h][n] = (h < F_) ? nodesT[h][n] : 0.0f;
  }

  const int jm = tid & 127;
  const int ng = tid >> 7;            // wave-uniform
  const int n0 = 4 * ng;
  const bool active = jm < 100;
  int cur = 0;

  for (int pass = 0; pass < 3; ++pass) {
    const int scr = cur ^ 1;
    float acc[4] = {0.f, 0.f, 0.f, 0.f};
    // ---- messages: per type, aggregate Y into scratch, then GEMM-acc -------
    for (int t = 0; t < 4; ++t) {
      __syncthreads();                // scratch free (previous readers done)
      for (int p = tid; p < N_ * H_; p += TB) {
        int h = p >> 5, n = p & 31;
        int cnt = sh_cnt[n] < CAP_ ? sh_cnt[n] : CAP_;
        float s = 0.0f;
        for (int e = 0; e < cnt; ++e) {
          int gt = sh_gt[n][e];
          if ((gt & 3) == t) s += sh_w[n][e] * buf[cur][h][gt >> 2];
        }
        buf[scr][h][n] = s;
      }
      __syncthreads();
      if (active) {
        const float* wcol = WmsgT + (t * H_) * M_ + jm;  // coalesced over jm
#pragma unroll 4
        for (int k = 0; k < H_; ++k) {
          float w = wcol[k * M_];
          float4 yv = *(const float4*)&buf[scr][k][n0];  // wave-uniform bcast
          acc[0] += w * yv.x;
          acc[1] += w * yv.y;
          acc[2] += w * yv.z;
          acc[3] += w * yv.w;
        }
      }
    }
    __syncthreads();
    if (active) *(float4*)&msgT[jm][n0] = *(float4*)acc;
    __syncthreads();
    // ---- GRU ---------------------------------------------------------------
    if (active) {
      float air[4] = {0,0,0,0}, aiz[4] = {0,0,0,0}, ain[4] = {0,0,0,0},
            ahr[4] = {0,0,0,0}, ahz[4] = {0,0,0,0}, ahn[4] = {0,0,0,0};
      const float* wi = WihT + jm;
      const float* wh = WhhT + jm;
#pragma unroll 2
      for (int k = 0; k < H_; ++k) {
        float wir = wi[k * 300], wiz = wi[k * 300 + 100], win = wi[k * 300 + 200];
        float whr = wh[k * 300], whz = wh[k * 300 + 100], whn = wh[k * 300 + 200];
        float4 xv = *(const float4*)&msgT[k][n0];
        float4 hv = *(const float4*)&buf[cur][k][n0];
        air[0] += wir * xv.x; air[1] += wir * xv.y; air[2] += wir * xv.z; air[3] += wir * xv.w;
        aiz[0] += wiz * xv.x; aiz[1] += wiz * xv.y; aiz[2] += wiz * xv.z; aiz[3] += wiz * xv.w;
        ain[0] += win * xv.x; ain[1] += win * xv.y; ain[2] += win * xv.z; ain[3] += win * xv.w;
        ahr[0] += whr * hv.x; ahr[1] += whr * hv.y; ahr[2] += whr * hv.z; ahr[3] += whr * hv.w;
        ahz[0] += whz * hv.x; ahz[1] += whz * hv.y; ahz[2] += whz * hv.z; ahz[3] += whz * hv.w;
        ahn[0] += whn * hv.x; ahn[1] += whn * hv.y; ahn[2] += whn * hv.z; ahn[3] += whn * hv.w;
      }
      float bir = b_ih[jm], biz = b_ih[100 + jm], bin_ = b_ih[200 + jm];
      float bhr = b_hh[jm], bhz = b_hh[100 + jm], bhn = b_hh[200 + jm];
      float hnew[4];
#pragma unroll
      for (int i = 0; i < 4; ++i) {
        int n = n0 + i;
        float ho = buf[cur][jm][n];
        float r = sigmoidf_(air[i] + bir + ahr[i] + bhr);
        float z = sigmoidf_(aiz[i] + biz + ahz[i] + bhz);
        float nn2 = tanhf(ain[i] + bin_ + r * (ahn[i] + bhn));
        float hv_ = (1.0f - z) * nn2 + z * ho;
        hnew[i] = (sh_rowsum[n] != 0.0f) ? hv_ : ho;
      }
      *(float4*)&buf[scr][jm][n0] = *(float4*)hnew;
    }
    __syncthreads();
    cur ^= 1;
  }

  // ---- readout: gate = sig([h,x]@Wg+bg); emb = gate*(h@We+be) --------------
  if (tid < H_) sh_ge[tid] = 0.0f;
  __syncthreads();
  if (active) {
    float ag[4] = {0,0,0,0}, ae[4] = {0,0,0,0};
#pragma unroll 4
    for (int k = 0; k < H_; ++k) {
      float wgv = Wg[k * H_ + jm];    // Wg is (H+F, H): already k-major
      float wev = We[k * H_ + jm];
      float4 hv = *(const float4*)&buf[cur][k][n0];
      ag[0] += wgv * hv.x; ag[1] += wgv * hv.y; ag[2] += wgv * hv.z; ag[3] += wgv * hv.w;
      ae[0] += wev * hv.x; ae[1] += wev * hv.y; ae[2] += wev * hv.z; ae[3] += wev * hv.w;
    }
#pragma unroll 4
    for (int f = 0; f < F_; ++f) {
      float wgv = Wg[(H_ + f) * H_ + jm];
      float4 nv = *(const float4*)&nodesT[f][n0];
      ag[0] += wgv * nv.x; ag[1] += wgv * nv.y; ag[2] += wgv * nv.z; ag[3] += wgv * nv.w;
    }
    float bgj = bg[jm], bej = be[jm];
    float psum = 0.0f;
#pragma unroll
    for (int i = 0; i < 4; ++i) {
      int n = n0 + i;
      float gate = sigmoidf_(ag[i] + bgj);
      float emb = gate * (ae[i] + bej);
      if (sh_rowsum[n] != 0.0f) psum += emb;     // node_mask
    }
    atomicAdd(&sh_ge[jm], psum);
  }
  __syncthreads();
  if (tid < OUT_) {
    float s = bo[tid];
#pragma unroll 4
    for (int k = 0; k < H_; ++k) s += sh_ge[k] * Wo[k * OUT_ + tid];
    out[(size_t)b * OUT_ + tid] = s;
  }
}

extern "C" void kernel_launch(void* const* d_in, const int* in_sizes, int n_in,
                              void* d_out, int out_size, void* d_ws, size_t ws_size,
                              hipStream_t stream) {
  const float* nodes = (const float*)d_in[0];
  const float* edges = (const float*)d_in[1];
  const float* W_msg = (const float*)d_in[2];
  const float* W_ih  = (const float*)d_in[3];
  const float* W_hh  = (const float*)d_in[4];
  const float* b_ih  = (const float*)d_in[5];
  const float* b_hh  = (const float*)d_in[6];
  const float* Wg    = (const float*)d_in[7];
  const float* bg    = (const float*)d_in[8];
  const float* We    = (const float*)d_in[9];
  const float* be    = (const float*)d_in[10];
  const float* Wo    = (const float*)d_in[11];
  const float* bo    = (const float*)d_in[12];

  float* WmsgT = (float*)d_ws;        // 40000 floats
  float* WihT  = WmsgT + 40000;       // 30000 floats
  float* WhhT  = WihT + 30000;        // 30000 floats

  prep_weights<<<(M_ * H_ * EF_ + 255) / 256, 256, 0, stream>>>(
      W_msg, W_ih, W_hh, WmsgT, WihT, WhhT);
  mpnn_fused<<<B_, TB, 0, stream>>>(nodes, edges, WmsgT, WihT, WhhT, b_ih, b_hh,
                                    Wg, bg, We, be, Wo, bo, (float*)d_out);
}

// Round 5
// 182.451 us; speedup vs baseline: 2.3298x; 1.3516x over previous
//
#include <hip/hip_runtime.h>
#include <cstddef>
#include <cstdint>

// B=256, N=32, F=40, H=M=100, EF=4, OUT=128, 3 passes.
#define B_   256
#define N_   32
#define F_   40
#define H_   100
#define OUT_ 128
#define CAP_ 8
#define TB   512          // 8 waves/block, 1 block/CU
#define XCS  168          // Xcat row stride (shorts): k 0..159 (+8 pad), 16B-mult
#define XMS  136          // Xm / Xy row stride (shorts): k 0..127 (+8 pad)
#define NBLK 343          // A-fragment blocks in workspace

using bf16x8 = __attribute__((ext_vector_type(8))) short;   // 8 bf16 (4 VGPRs)
using f32x4  = __attribute__((ext_vector_type(4))) float;   // MFMA C/D

__device__ __forceinline__ float sigmoidf_(float x){ return 1.0f/(1.0f+__expf(-x)); }
__device__ __forceinline__ float bf2f(short s){ return __uint_as_float(((uint32_t)(uint16_t)s)<<16); }
__device__ __forceinline__ short f2bf(float x){            // round-to-nearest-even
  uint32_t u = __float_as_uint(x);
  return (short)((u + 0x7FFFu + ((u>>16)&1u))>>16);
}
__device__ __forceinline__ void bsplit(float x, short& hi, short& lo){
  hi = f2bf(x);
  lo = f2bf(x - bf2f(hi));
}

// ---------------------------------------------------------------------------
// Pre-pack every weight matrix into MFMA A-operand fragments, hi/lo bf16.
// Block table (each block = one (tile,kstep): 64 lanes x {8 hi, 8 lo} shorts):
//   [0,112)   W_msg  : t<4, jmt<7, ks<4     A[m][k]=W_msg[m, k, t]
//   [112,280) GRU    : mat<6 (ihr,ihz,ihn,hhr,hhz,hhn), jmt<7, ks<4
//   [280,315) Wg^T   : jmt<7, ks<5 (K=140)  A[j][k]=Wg[k, j]
//   [315,343) We^T   : jmt<7, ks<4          A[j][k]=We[k, j]
// Lane layout (verified m120/m89): A[m=lane&15][k=(lane>>4)*8+j].
// Out-of-range rows/cols stored as 0 (this is what lets the combined Xcat
// buffer carry node features in k-rows 100..139 without polluting the GRU).
// ---------------------------------------------------------------------------
__global__ void prep_frags(const float* __restrict__ Wmsg,
                           const float* __restrict__ Wih,
                           const float* __restrict__ Whh,
                           const float* __restrict__ Wg,
                           const float* __restrict__ We,
                           short* __restrict__ AF){
  int t0 = blockIdx.x*blockDim.x + threadIdx.x;
  if (t0 >= NBLK*64) return;
  int blk = t0>>6, lane = t0&63;
  int m = lane&15, q = lane>>4;
  short* dst = AF + (size_t)blk*1024 + lane*16;
  for (int j=0;j<8;++j){
    int kl = q*8 + j;
    float v = 0.0f;
    if (blk < 112){
      int t = blk/28, rem = blk%28, jmt = rem>>2, ks = rem&3;
      int mg = jmt*16+m, k = ks*32+kl;
      if (mg<100 && k<100) v = Wmsg[(mg*100+k)*4 + t];
    } else if (blk < 280){
      int bb = blk-112, mat = bb/28, rem = bb%28, jmt = rem>>2, ks = rem&3;
      int mg = jmt*16+m, k = ks*32+kl;
      if (mg<100 && k<100)
        v = (mat<3) ? Wih[(mat*100+mg)*100+k] : Whh[((mat-3)*100+mg)*100+k];
    } else if (blk < 315){
      int bb = blk-280, jmt = bb/5, ks = bb%5;
      int mg = jmt*16+m, k = ks*32+kl;
      if (mg<100 && k<140) v = Wg[k*100+mg];
    } else {
      int bb = blk-315, jmt = bb>>2, ks = bb&3;
      int mg = jmt*16+m, k = ks*32+kl;
      if (mg<100 && k<100) v = We[k*100+mg];
    }
    short hi,lo; bsplit(v,hi,lo);
    dst[j] = hi; dst[8+j] = lo;
  }
}

// B-operand fragment from an LDS [n][k] bf16 buffer: lane holds
// B[k=(lane>>4)*8+j][n=lane&15] -> 8 contiguous k-shorts (16B aligned).
__device__ __forceinline__ bf16x8 ldB(const short* X, int stride, int nt, int ks, int lane){
  int n = nt*16 + (lane&15);
  return *(const bf16x8*)&X[n*stride + ks*32 + (lane>>4)*8];
}
// C += Ahi*Bhi + Ahi*Blo + Alo*Bhi  (split-bf16 triple product)
__device__ __forceinline__ f32x4 mm3(const short* __restrict__ AF, int blk, int lane,
                                     bf16x8 bh, bf16x8 bl, f32x4 c){
  const short* pa = AF + (size_t)blk*1024 + lane*16;
  bf16x8 ah = *(const bf16x8*)pa;
  bf16x8 al = *(const bf16x8*)(pa+8);
  c = __builtin_amdgcn_mfma_f32_16x16x32_bf16(ah, bh, c, 0,0,0);
  c = __builtin_amdgcn_mfma_f32_16x16x32_bf16(ah, bl, c, 0,0,0);
  c = __builtin_amdgcn_mfma_f32_16x16x32_bf16(al, bh, c, 0,0,0);
  return c;
}

// ---------------------------------------------------------------------------
// Fused MPNN, one block per batch, 512 threads (8 waves).
// 14 MFMA tile-tasks (7 jm-tiles x 2 n-tiles); wave w owns tasks w and w+8.
// All activations kept as hi/lo bf16 B-operand buffers in LDS; gate sums stay
// in C-fragments (no gate LDS buffers). C/D: col=lane&15, row=(lane>>4)*4+reg.
// ---------------------------------------------------------------------------
__global__ __launch_bounds__(TB) void mpnn_mfma(
    const float* __restrict__ nodes, const float* __restrict__ edges,
    const short* __restrict__ AF,
    const float* __restrict__ b_ih, const float* __restrict__ b_hh,
    const float* __restrict__ bg, const float* __restrict__ be,
    const float* __restrict__ Wo, const float* __restrict__ bo,
    float* __restrict__ out){
  const int b = blockIdx.x;
  const int tid = threadIdx.x;
  const int lane = tid & 63;
  const int w = tid >> 6;

  __shared__ short XcH[32*XCS], XcL[32*XCS];   // cat: h(0..99) | nodes(100..139) | 0
  __shared__ short XmH[32*XMS], XmL[32*XMS];   // messages
  __shared__ short XyH[32*XMS], XyL[32*XMS];   // per-type aggregated Y_t
  __shared__ float sh_ge[H_];
  __shared__ float sh_rowsum[N_];
  __shared__ int   sh_cnt[N_];
  __shared__ int   sh_gt[N_][CAP_];            // packed (g<<2)|t
  __shared__ float sh_w[N_][CAP_];

  // ---- zero LDS ------------------------------------------------------------
  for (int i=tid;i<(32*XCS)/2;i+=TB){ ((int*)XcH)[i]=0; ((int*)XcL)[i]=0; }
  for (int i=tid;i<(32*XMS)/2;i+=TB){ ((int*)XmH)[i]=0; ((int*)XmL)[i]=0;
                                      ((int*)XyH)[i]=0; ((int*)XyL)[i]=0; }
  if (tid < H_) sh_ge[tid]=0.0f;
  if (tid < N_){ sh_cnt[tid]=0; sh_rowsum[tid]=0.0f; }
  __syncthreads();

  // ---- per-node neighbor lists + node staging ------------------------------
  for (int p=tid; p<N_*N_; p+=TB){
    int n = p>>5, g = p&31;
    const float* e = edges + (((size_t)b*N_+n)*N_+g)*4;
    float e0=e[0], e1=e[1], e2=e[2], e3=e[3];
    float adj = e0+e1+e2+e3;
    if (adj != 0.0f){
      atomicAdd(&sh_rowsum[n], adj);
      float ef[4] = {e0,e1,e2,e3};
      for (int f=0; f<4; ++f)
        if (ef[f] != 0.0f){
          int s = atomicAdd(&sh_cnt[n],1);
          if (s<CAP_){ sh_gt[n][s]=(g<<2)|f; sh_w[n][s]=ef[f]; }
        }
    }
  }
  for (int p=tid; p<N_*F_; p+=TB){
    int n = p/F_, f = p%F_;
    float x = nodes[((size_t)b*N_+n)*F_ + f];
    short hi,lo; bsplit(x,hi,lo);
    XcH[n*XCS+f]=hi;      XcL[n*XCS+f]=lo;        // h init rows 0..39
    XcH[n*XCS+100+f]=hi;  XcL[n*XCS+100+f]=lo;    // cat-tail rows 100..139
  }
  __syncthreads();

  // task decode helper values
  // tk = w + 8*rnd; jmt = tk>>1; nt = tk&1
  for (int pass=0; pass<3; ++pass){
    // ---- messages: C_msg += sum_t W_t * Y_t --------------------------------
    f32x4 Cm[2]; Cm[0]=(f32x4)0.0f; Cm[1]=(f32x4)0.0f;
    for (int t=0;t<4;++t){
      for (int p=tid;p<N_*H_;p+=TB){         // build Y_t (fp32 -> split bf16)
        int k = p>>5, n = p&31;
        int cnt = sh_cnt[n] < CAP_ ? sh_cnt[n] : CAP_;
        float s = 0.0f;
        for (int e=0;e<cnt;++e){
          int gt = sh_gt[n][e];
          if ((gt&3)==t){
            int g = gt>>2;
            s += sh_w[n][e]*(bf2f(XcH[g*XCS+k])+bf2f(XcL[g*XCS+k]));
          }
        }
        short hi,lo; bsplit(s,hi,lo);
        XyH[n*XMS+k]=hi; XyL[n*XMS+k]=lo;
      }
      __syncthreads();
      for (int rnd=0;rnd<2;++rnd){
        int tk = w + 8*rnd;
        if (tk<14){
          int jmt = tk>>1, nt = tk&1;
          for (int ks=0;ks<4;++ks){
            bf16x8 bh = ldB(XyH,XMS,nt,ks,lane), bl = ldB(XyL,XMS,nt,ks,lane);
            Cm[rnd] = mm3(AF, (t*7+jmt)*4+ks, lane, bh, bl, Cm[rnd]);
          }
        }
      }
      __syncthreads();                       // Y_t consumed; safe to rebuild
    }
    // write messages -> Xm (rows<100)
    for (int rnd=0;rnd<2;++rnd){
      int tk = w + 8*rnd;
      if (tk<14){
        int jmt = tk>>1, nt = tk&1, n = nt*16+(lane&15);
        for (int r=0;r<4;++r){
          int row = jmt*16 + (lane>>4)*4 + r;
          if (row<100){
            short hi,lo; bsplit(Cm[rnd][r],hi,lo);
            XmH[n*XMS+row]=hi; XmL[n*XMS+row]=lo;
          }
        }
      }
    }
    __syncthreads();
    // ---- GRU gate GEMMs: Cr=ir+hr, Cz=iz+hz, Ci=in, Ch=hn ------------------
    f32x4 Cr[2],Cz[2],Ci[2],Ch[2];
    Cr[0]=Cr[1]=Cz[0]=Cz[1]=Ci[0]=Ci[1]=Ch[0]=Ch[1]=(f32x4)0.0f;
    for (int rnd=0;rnd<2;++rnd){
      int tk = w + 8*rnd;
      if (tk<14){
        int jmt = tk>>1, nt = tk&1;
        for (int ks=0;ks<4;++ks){
          bf16x8 bmh = ldB(XmH,XMS,nt,ks,lane), bml = ldB(XmL,XMS,nt,ks,lane);
          bf16x8 bhh = ldB(XcH,XCS,nt,ks,lane), bhl = ldB(XcL,XCS,nt,ks,lane);
          int base = 112 + jmt*4 + ks;
          Cr[rnd] = mm3(AF, base + 0*28, lane, bmh, bml, Cr[rnd]);  // ih_r
          Cr[rnd] = mm3(AF, base + 3*28, lane, bhh, bhl, Cr[rnd]);  // hh_r
          Cz[rnd] = mm3(AF, base + 1*28, lane, bmh, bml, Cz[rnd]);  // ih_z
          Cz[rnd] = mm3(AF, base + 4*28, lane, bhh, bhl, Cz[rnd]);  // hh_z
          Ci[rnd] = mm3(AF, base + 2*28, lane, bmh, bml, Ci[rnd]);  // ih_n
          Ch[rnd] = mm3(AF, base + 5*28, lane, bhh, bhl, Ch[rnd]);  // hh_n
        }
      }
    }
    __syncthreads();                         // all Xc/Xm reads done
    // ---- GRU elementwise: update h rows of Xcat in place -------------------
    for (int rnd=0;rnd<2;++rnd){
      int tk = w + 8*rnd;
      if (tk<14){
        int jmt = tk>>1, nt = tk&1, n = nt*16+(lane&15);
        bool msk = (sh_rowsum[n] != 0.0f);
        for (int r=0;r<4;++r){
          int row = jmt*16 + (lane>>4)*4 + r;
          if (row<100){
            float ho = bf2f(XcH[n*XCS+row]) + bf2f(XcL[n*XCS+row]);
            float rr = sigmoidf_(Cr[rnd][r] + b_ih[row]     + b_hh[row]);
            float zz = sigmoidf_(Cz[rnd][r] + b_ih[100+row] + b_hh[100+row]);
            float nn = tanhf(Ci[rnd][r] + b_ih[200+row] + rr*(Ch[rnd][r] + b_hh[200+row]));
            float hnew = (1.0f-zz)*nn + zz*ho;
            if (!msk) hnew = ho;
            short hi,lo; bsplit(hnew,hi,lo);
            XcH[n*XCS+row]=hi; XcL[n*XCS+row]=lo;
          }
        }
      }
    }
    __syncthreads();
  }

  // ---- readout: gate = sig(cat@Wg+bg), emb = gate*(h@We+be), masked sum ----
  f32x4 Cg[2],Ce[2]; Cg[0]=Cg[1]=Ce[0]=Ce[1]=(f32x4)0.0f;
  for (int rnd=0;rnd<2;++rnd){
    int tk = w + 8*rnd;
    if (tk<14){
      int jmt = tk>>1, nt = tk&1;
      for (int ks=0;ks<5;++ks){              // K=140 (pad 160): Xcat has cat rows
        bf16x8 bh = ldB(XcH,XCS,nt,ks,lane), bl = ldB(XcL,XCS,nt,ks,lane);
        Cg[rnd] = mm3(AF, 280 + jmt*5 + ks, lane, bh, bl, Cg[rnd]);
      }
      for (int ks=0;ks<4;++ks){              // K=100: We zero-padded kills rows>=100
        bf16x8 bh = ldB(XcH,XCS,nt,ks,lane), bl = ldB(XcL,XCS,nt,ks,lane);
        Ce[rnd] = mm3(AF, 315 + jmt*4 + ks, lane, bh, bl, Ce[rnd]);
      }
    }
  }
  for (int rnd=0;rnd<2;++rnd){
    int tk = w + 8*rnd;
    if (tk<14){
      int jmt = tk>>1, nt = tk&1, n = nt*16+(lane&15);
      bool msk = (sh_rowsum[n] != 0.0f);
      for (int r=0;r<4;++r){
        int row = jmt*16 + (lane>>4)*4 + r;
        float v = 0.0f;
        if (row<100){
          float gate = sigmoidf_(Cg[rnd][r] + bg[row]);
          float emb  = gate*(Ce[rnd][r] + be[row]);
          v = msk ? emb : 0.0f;
        }
        v += __shfl_xor(v, 1);               // reduce across 16 cols
        v += __shfl_xor(v, 2);
        v += __shfl_xor(v, 4);
        v += __shfl_xor(v, 8);
        if (row<100 && (lane&15)==0) atomicAdd(&sh_ge[row], v);
      }
    }
  }
  __syncthreads();
  // ---- out = graph_emb @ Wo + bo -------------------------------------------
  if (tid < OUT_){
    float s = bo[tid];
#pragma unroll 4
    for (int k=0;k<H_;++k) s += sh_ge[k]*Wo[k*OUT_+tid];
    out[(size_t)b*OUT_ + tid] = s;
  }
}

extern "C" void kernel_launch(void* const* d_in, const int* in_sizes, int n_in,
                              void* d_out, int out_size, void* d_ws, size_t ws_size,
                              hipStream_t stream){
  const float* nodes = (const float*)d_in[0];
  const float* edges = (const float*)d_in[1];
  const float* W_msg = (const float*)d_in[2];
  const float* W_ih  = (const float*)d_in[3];
  const float* W_hh  = (const float*)d_in[4];
  const float* b_ih  = (const float*)d_in[5];
  const float* b_hh  = (const float*)d_in[6];
  const float* Wg    = (const float*)d_in[7];
  const float* bg    = (const float*)d_in[8];
  const float* We    = (const float*)d_in[9];
  const float* be    = (const float*)d_in[10];
  const float* Wo    = (const float*)d_in[11];
  const float* bo    = (const float*)d_in[12];

  short* AF = (short*)d_ws;                 // 343*1024 shorts = 686 KB

  prep_frags<<<(NBLK*64 + 255)/256, 256, 0, stream>>>(W_msg, W_ih, W_hh, Wg, We, AF);
  mpnn_mfma<<<B_, TB, 0, stream>>>(nodes, edges, AF, b_ih, b_hh, bg, be, Wo, bo,
                                   (float*)d_out);
}